// Round 1
// baseline (1496.617 us; speedup 1.0000x reference)
//
#include <hip/hip_runtime.h>

typedef _Float16 f16;
typedef f16 f16x8 __attribute__((ext_vector_type(8)));
typedef f16 f16x4 __attribute__((ext_vector_type(4)));
typedef float f32x4 __attribute__((ext_vector_type(4)));

#define S_LEN 2048
#define D_MODEL 2048
#define NHEADS 8
#define DQ 128
#define DV 256
#define NCOL 6144   // q(1024) | k(1024) | v(2048) | og(2048)
#define NROWS 4096  // B*S

// ---------------- f32 -> f16 cast ----------------
__global__ __launch_bounds__(256) void cast_kernel(const float* __restrict__ in,
                                                   f16* __restrict__ out, int n4) {
    int i = blockIdx.x * 256 + threadIdx.x;
    if (i < n4) {
        float4 v = reinterpret_cast<const float4*>(in)[i];
        f16x4 o = { (f16)v.x, (f16)v.y, (f16)v.z, (f16)v.w };
        reinterpret_cast<f16x4*>(out)[i] = o;
    }
}

// ---------------- GEMM: C[M,N] = A[M,K] @ B[N,K]^T  (f16 in, f32 out) ----------------
// 128x128 block tile, 4 waves (2x2), each wave 64x64 via 4x4 mfma_f32_16x16x32_f16.
__global__ __launch_bounds__(256) void gemm_f16(const f16* __restrict__ A,
                                                const f16* __restrict__ B,
                                                float* __restrict__ C,
                                                int M, int N, int K, int ldc,
                                                int scale_cols, float scale) {
    const int tid  = threadIdx.x;
    const int lane = tid & 63;
    const int w    = tid >> 6;
    const int wr   = w >> 1, wc = w & 1;
    const int m0   = blockIdx.y * 128, n0 = blockIdx.x * 128;
    const int r16  = lane & 15;
    const int kg   = (lane >> 4) * 8;

    const f16* Ap = A + (size_t)(m0 + wr * 64 + r16) * K + kg;
    const f16* Bp = B + (size_t)(n0 + wc * 64 + r16) * K + kg;

    f32x4 acc[4][4];
#pragma unroll
    for (int i = 0; i < 4; i++)
#pragma unroll
        for (int j = 0; j < 4; j++) acc[i][j] = (f32x4){0.f, 0.f, 0.f, 0.f};

    for (int k0 = 0; k0 < K; k0 += 32) {
        f16x8 a[4], b[4];
#pragma unroll
        for (int i = 0; i < 4; i++)
            a[i] = *reinterpret_cast<const f16x8*>(Ap + (size_t)i * 16 * K + k0);
#pragma unroll
        for (int j = 0; j < 4; j++)
            b[j] = *reinterpret_cast<const f16x8*>(Bp + (size_t)j * 16 * K + k0);
#pragma unroll
        for (int i = 0; i < 4; i++)
#pragma unroll
            for (int j = 0; j < 4; j++)
                acc[i][j] = __builtin_amdgcn_mfma_f32_16x16x32_f16(a[i], b[j], acc[i][j], 0, 0, 0);
    }

    const int crow = m0 + wr * 64 + (lane >> 4) * 4;
    const int ccol = n0 + wc * 64 + r16;
#pragma unroll
    for (int i = 0; i < 4; i++) {
#pragma unroll
        for (int j = 0; j < 4; j++) {
            const int col = ccol + j * 16;
            const float sc = (col < scale_cols) ? scale : 1.f;
#pragma unroll
            for (int r = 0; r < 4; r++) {
                C[(size_t)(crow + i * 16 + r) * ldc + col] = acc[i][j][r] * sc;
            }
        }
    }
}

// ---------------- gates: exact f32; stores (i_capped, log_sigmoid(f_capped)) ----------------
__global__ __launch_bounds__(256) void gate_kernel(const float* __restrict__ x,
                                                   const float* __restrict__ Wig,
                                                   const float* __restrict__ big,
                                                   const float* __restrict__ Wfg,
                                                   const float* __restrict__ bfg,
                                                   float* __restrict__ gates) {
    __shared__ float xs[4][D_MODEL];
    const int tid  = threadIdx.x;
    const int row0 = blockIdx.x * 4;
#pragma unroll
    for (int r = 0; r < 4; ++r) {
        const float4 v0 = *reinterpret_cast<const float4*>(&x[(size_t)(row0 + r) * D_MODEL + tid * 8]);
        const float4 v1 = *reinterpret_cast<const float4*>(&x[(size_t)(row0 + r) * D_MODEL + tid * 8 + 4]);
        *reinterpret_cast<float4*>(&xs[r][tid * 8])     = v0;
        *reinterpret_cast<float4*>(&xs[r][tid * 8 + 4]) = v1;
    }
    __syncthreads();

    const int o = tid >> 4;  // 0..15; o<8 -> i-gate head o, else f-gate head o-8
    const int t = tid & 15;
    const int head = o & 7;
    const bool is_i = (o < 8);
    const float* W = (is_i ? Wig : Wfg) + (size_t)head * D_MODEL;

    float a0 = 0.f, a1 = 0.f, a2 = 0.f, a3 = 0.f;
    for (int j = t * 128; j < t * 128 + 128; j += 4) {
        const float4 wv = *reinterpret_cast<const float4*>(&W[j]);
        const float4 xa = *reinterpret_cast<const float4*>(&xs[0][j]);
        const float4 xb = *reinterpret_cast<const float4*>(&xs[1][j]);
        const float4 xc = *reinterpret_cast<const float4*>(&xs[2][j]);
        const float4 xd = *reinterpret_cast<const float4*>(&xs[3][j]);
        a0 += wv.x * xa.x + wv.y * xa.y + wv.z * xa.z + wv.w * xa.w;
        a1 += wv.x * xb.x + wv.y * xb.y + wv.z * xb.z + wv.w * xb.w;
        a2 += wv.x * xc.x + wv.y * xc.y + wv.z * xc.z + wv.w * xc.w;
        a3 += wv.x * xd.x + wv.y * xd.y + wv.z * xd.z + wv.w * xd.w;
    }
#pragma unroll
    for (int off = 1; off < 16; off <<= 1) {
        a0 += __shfl_xor(a0, off);
        a1 += __shfl_xor(a1, off);
        a2 += __shfl_xor(a2, off);
        a3 += __shfl_xor(a3, off);
    }
    if (t == 0) {
        const float bias = is_i ? big[head] : bfg[head];
        float accs[4] = {a0, a1, a2, a3};
#pragma unroll
        for (int r = 0; r < 4; ++r) {
            const float pre = accs[r] + bias;
            const float capped = 15.f * tanhf(pre * (1.f / 15.f));
            float val;
            if (is_i) val = capped;
            else      val = fminf(capped, 0.f) - log1pf(expf(-fabsf(capped)));
            gates[(size_t)(row0 + r) * 16 + head * 2 + (is_i ? 0 : 1)] = val;
        }
    }
}

// ---------------- sequential mLSTM scan ----------------
// grid = 16 (b,h) * 32 v-chunks = 512 blocks; 256 threads: dg(0..31) x vg(0..7).
// Thread owns C[4 d's][1 v], replicated n[4 d's], replicated m. No barriers in loop.
__global__ __launch_bounds__(256) void scan_kernel(const float* __restrict__ QKVO,
                                                   const float* __restrict__ gates,
                                                   float* __restrict__ hbuf,
                                                   float* __restrict__ Cout,
                                                   float* __restrict__ nout,
                                                   float* __restrict__ mout) {
    const int blk = blockIdx.x;   // bh*32 + vc
    const int bh  = blk >> 5;
    const int vcb = blk & 31;
    const int b   = bh >> 3;
    const int hh  = bh & 7;
    const int tid = threadIdx.x;
    const int dg  = tid & 31;
    const int vg  = tid >> 5;
    const int dbase = dg * 4;
    const int vloc  = vcb * 8 + vg;   // v index within head (0..255)

    __shared__ float2 gif[S_LEN];     // (i, f_log) per step, 16 KiB
    for (int t = tid; t < S_LEN; t += 256)
        gif[t] = *reinterpret_cast<const float2*>(&gates[(size_t)(b * S_LEN + t) * 16 + hh * 2]);
    __syncthreads();

    const float* qptr = QKVO + (size_t)b * S_LEN * NCOL + hh * DQ + dbase;  // q pre-scaled
    const float* kptr = qptr + 1024;
    const float* vptr = QKVO + (size_t)b * S_LEN * NCOL + 2048 + hh * DV + vloc;
    float* hptr = hbuf + (size_t)b * S_LEN * D_MODEL + hh * DV + vloc;

    float c0 = 0.f, c1 = 0.f, c2 = 0.f, c3 = 0.f;
    float n0 = 0.f, n1 = 0.f, n2 = 0.f, n3 = 0.f;
    float m = 0.f;

    float4 qa = *reinterpret_cast<const float4*>(qptr);
    float4 ka = *reinterpret_cast<const float4*>(kptr);
    float  va = vptr[0];
    float4 qb = *reinterpret_cast<const float4*>(qptr + NCOL);
    float4 kb = *reinterpret_cast<const float4*>(kptr + NCOL);
    float  vb = vptr[NCOL];

#define STEP(Q, K, V, T)                                                          \
    {                                                                             \
        const float2 g = gif[(T)];                                                \
        const float mn = fmaxf(g.y + m, g.x);                                     \
        const float F = __expf(g.y + m - mn);                                     \
        const float I = __expf(g.x - mn);                                         \
        const float ik0 = I * (K).x, ik1 = I * (K).y;                             \
        const float ik2 = I * (K).z, ik3 = I * (K).w;                             \
        n0 = fmaf(F, n0, ik0); n1 = fmaf(F, n1, ik1);                             \
        n2 = fmaf(F, n2, ik2); n3 = fmaf(F, n3, ik3);                             \
        c0 = fmaf(F, c0, ik0 * (V)); c1 = fmaf(F, c1, ik1 * (V));                 \
        c2 = fmaf(F, c2, ik2 * (V)); c3 = fmaf(F, c3, ik3 * (V));                 \
        float qn = (Q).x * n0 + (Q).y * n1 + (Q).z * n2 + (Q).w * n3;             \
        float hs = (Q).x * c0 + (Q).y * c1 + (Q).z * c2 + (Q).w * c3;             \
        qn += __shfl_xor(qn, 1);  hs += __shfl_xor(hs, 1);                        \
        qn += __shfl_xor(qn, 2);  hs += __shfl_xor(hs, 2);                        \
        qn += __shfl_xor(qn, 4);  hs += __shfl_xor(hs, 4);                        \
        qn += __shfl_xor(qn, 8);  hs += __shfl_xor(hs, 8);                        \
        qn += __shfl_xor(qn, 16); hs += __shfl_xor(hs, 16);                       \
        const float dnm = fmaxf(fabsf(qn), __expf(-mn)) + 1e-6f;                  \
        if (dg == 0) hptr[(size_t)(T) * D_MODEL] = hs * __builtin_amdgcn_rcpf(dnm); \
        m = mn;                                                                   \
    }

    for (int t = 0; t < S_LEN; t += 2) {
        const int t2 = (t + 2 < S_LEN) ? t + 2 : S_LEN - 1;
        const int t3 = (t + 3 < S_LEN) ? t + 3 : S_LEN - 1;
        const float4 qc = *reinterpret_cast<const float4*>(qptr + (size_t)t2 * NCOL);
        const float4 kc = *reinterpret_cast<const float4*>(kptr + (size_t)t2 * NCOL);
        const float  vc2 = vptr[(size_t)t2 * NCOL];
        const float4 qd = *reinterpret_cast<const float4*>(qptr + (size_t)t3 * NCOL);
        const float4 kd = *reinterpret_cast<const float4*>(kptr + (size_t)t3 * NCOL);
        const float  vd = vptr[(size_t)t3 * NCOL];
        STEP(qa, ka, va, t);
        STEP(qb, kb, vb, t + 1);
        qa = qc; ka = kc; va = vc2;
        qb = qd; kb = kd; vb = vd;
    }
#undef STEP

    // final state
    float* Cp = Cout + (size_t)bh * DQ * DV;
    Cp[(size_t)(dbase + 0) * DV + vloc] = c0;
    Cp[(size_t)(dbase + 1) * DV + vloc] = c1;
    Cp[(size_t)(dbase + 2) * DV + vloc] = c2;
    Cp[(size_t)(dbase + 3) * DV + vloc] = c3;
    if (vcb == 0 && vg == 0) {
        nout[(size_t)bh * DQ + dbase + 0] = n0;
        nout[(size_t)bh * DQ + dbase + 1] = n1;
        nout[(size_t)bh * DQ + dbase + 2] = n2;
        nout[(size_t)bh * DQ + dbase + 3] = n3;
        if (dg == 0) mout[bh] = m;
    }
}

// ---------------- per-head layernorm * gamma * sigmoid(og), f32 -> f16 ----------------
__global__ __launch_bounds__(256) void norm_kernel(const float* __restrict__ hbuf,
                                                   const float* __restrict__ QKVO,
                                                   const float* __restrict__ gamma,
                                                   f16* __restrict__ hout) {
    const int row = blockIdx.x;
    const int tid = threadIdx.x;
    const int g = tid >> 5;   // head
    const int l = tid & 31;
    const float* hrow = hbuf + (size_t)row * D_MODEL + g * DV;
    const float4 a  = *reinterpret_cast<const float4*>(&hrow[l * 8]);
    const float4 bb = *reinterpret_cast<const float4*>(&hrow[l * 8 + 4]);
    float s  = a.x + a.y + a.z + a.w + bb.x + bb.y + bb.z + bb.w;
    float s2 = a.x*a.x + a.y*a.y + a.z*a.z + a.w*a.w
             + bb.x*bb.x + bb.y*bb.y + bb.z*bb.z + bb.w*bb.w;
#pragma unroll
    for (int off = 1; off < 32; off <<= 1) {
        s  += __shfl_xor(s, off);
        s2 += __shfl_xor(s2, off);
    }
    const float mu  = s * (1.f / 256.f);
    const float var = s2 * (1.f / 256.f) - mu * mu;
    const float rs  = rsqrtf(var + 1e-6f);
    const float* ogr = QKVO + (size_t)row * NCOL + 4096 + g * DV + l * 8;
    const float* gam = gamma + g * DV + l * 8;
    const float hv[8] = {a.x, a.y, a.z, a.w, bb.x, bb.y, bb.z, bb.w};
    f16x8 o;
#pragma unroll
    for (int e = 0; e < 8; e++) {
        const float og  = ogr[e];
        const float sig = __builtin_amdgcn_rcpf(1.f + __expf(-og));
        const float hn  = (hv[e] - mu) * rs * gam[e];
        o[e] = (f16)(sig * hn);
    }
    *reinterpret_cast<f16x8*>(&hout[(size_t)row * D_MODEL + g * DV + l * 8]) = o;
}

// ---------------- launch ----------------
extern "C" void kernel_launch(void* const* d_in, const int* in_sizes, int n_in,
                              void* d_out, int out_size, void* d_ws, size_t ws_size,
                              hipStream_t stream) {
    (void)in_sizes; (void)n_in; (void)out_size; (void)ws_size;
    const float* x     = (const float*)d_in[0];
    const float* Wq    = (const float*)d_in[1];
    const float* Wk    = (const float*)d_in[2];
    const float* Wv    = (const float*)d_in[3];
    const float* Wog   = (const float*)d_in[4];
    const float* Wig   = (const float*)d_in[5];
    const float* big   = (const float*)d_in[6];
    const float* Wfg   = (const float*)d_in[7];
    const float* bfg   = (const float*)d_in[8];
    const float* gamma = (const float*)d_in[9];
    const float* Wout  = (const float*)d_in[10];

    char* ws = (char*)d_ws;
    size_t off = 0;
    f16*   xf    = (f16*)(ws + off);   off += (size_t)NROWS * D_MODEL * 2;   // 16.8 MB
    f16*   wcat  = (f16*)(ws + off);   off += (size_t)NCOL * D_MODEL * 2;    // 25.2 MB
    f16*   woutf = (f16*)(ws + off);   off += (size_t)D_MODEL * D_MODEL * 2; // 8.4 MB
    float* qkvo  = (float*)(ws + off); off += (size_t)NROWS * NCOL * 4;      // 100.7 MB
    float* gates = (float*)(ws + off); off += (size_t)NROWS * 16 * 4;        // 0.26 MB
    float* hbuf  = (float*)(ws + off); off += (size_t)NROWS * D_MODEL * 4;   // 33.6 MB
    f16*   houtf = xf;  // xf dead after GEMM1; reuse

    float* y  = (float*)d_out;
    float* Cf = y + (size_t)NROWS * D_MODEL;      // 2*8*128*256
    float* nf = Cf + (size_t)2 * 8 * 128 * 256;   // 2*8*128
    float* mf = nf + (size_t)2 * 8 * 128;         // 2*8

    // casts
    cast_kernel<<<(NROWS * D_MODEL / 4 + 255) / 256, 256, 0, stream>>>(x, xf, NROWS * D_MODEL / 4);
    cast_kernel<<<(1024 * 2048 / 4 + 255) / 256, 256, 0, stream>>>(Wq, wcat, 1024 * 2048 / 4);
    cast_kernel<<<(1024 * 2048 / 4 + 255) / 256, 256, 0, stream>>>(Wk, wcat + (size_t)1024 * 2048, 1024 * 2048 / 4);
    cast_kernel<<<(2048 * 2048 / 4 + 255) / 256, 256, 0, stream>>>(Wv, wcat + (size_t)2048 * 2048, 2048 * 2048 / 4);
    cast_kernel<<<(2048 * 2048 / 4 + 255) / 256, 256, 0, stream>>>(Wog, wcat + (size_t)4096 * 2048, 2048 * 2048 / 4);
    cast_kernel<<<(2048 * 2048 / 4 + 255) / 256, 256, 0, stream>>>(Wout, woutf, 2048 * 2048 / 4);

    // gates (exact f32)
    gate_kernel<<<NROWS / 4, 256, 0, stream>>>(x, Wig, big, Wfg, bfg, gates);

    // fused qkvo projection; q columns (<1024) pre-scaled by DQ^-0.5
    gemm_f16<<<dim3(NCOL / 128, NROWS / 128), 256, 0, stream>>>(
        xf, wcat, qkvo, NROWS, NCOL, D_MODEL, NCOL, 1024, 0.08838834764831845f);

    // sequential scan
    scan_kernel<<<512, 256, 0, stream>>>(qkvo, gates, hbuf, Cf, nf, mf);

    // multihead norm + output gate
    norm_kernel<<<NROWS, 256, 0, stream>>>(hbuf, qkvo, gamma, houtf);

    // y = h_out @ Wout^T
    gemm_f16<<<dim3(D_MODEL / 128, NROWS / 128), 256, 0, stream>>>(
        houtf, woutf, y, NROWS, D_MODEL, D_MODEL, D_MODEL, 0, 1.f);
}

// Round 3
// 712.756 us; speedup vs baseline: 2.0998x; 2.0998x over previous
//
#include <hip/hip_runtime.h>

typedef _Float16 f16;
typedef f16 f16x8 __attribute__((ext_vector_type(8)));
typedef f16 f16x4 __attribute__((ext_vector_type(4)));
typedef float f32x4 __attribute__((ext_vector_type(4)));

#define S_LEN 2048
#define D_MODEL 2048
#define NHEADS 8
#define DQ 128
#define DV 256
#define NCOL 6144   // q(1024) | k(1024) | v(2048) | og(2048)
#define NROWS 4096  // B*S
#define CHUNK 64
#define NCHUNK 32   // per sequence

// ---------------- f32 -> f16 cast ----------------
__global__ __launch_bounds__(256) void cast_kernel(const float* __restrict__ in,
                                                   f16* __restrict__ out, int n4) {
    int i = blockIdx.x * 256 + threadIdx.x;
    if (i < n4) {
        float4 v = reinterpret_cast<const float4*>(in)[i];
        f16x4 o = { (f16)v.x, (f16)v.y, (f16)v.z, (f16)v.w };
        reinterpret_cast<f16x4*>(out)[i] = o;
    }
}

// ---------------- GEMM: C[M,N] = A[M,K] @ B[N,K]^T  (f16 in, OT out) ----------------
template <typename OT>
__global__ __launch_bounds__(256) void gemm_f16(const f16* __restrict__ A,
                                                const f16* __restrict__ B,
                                                OT* __restrict__ C,
                                                int M, int N, int K, int ldc,
                                                int scale_cols, float scale) {
    const int tid  = threadIdx.x;
    const int lane = tid & 63;
    const int w    = tid >> 6;
    const int wr   = w >> 1, wc = w & 1;
    const int m0   = blockIdx.y * 128, n0 = blockIdx.x * 128;
    const int r16  = lane & 15;
    const int kg   = (lane >> 4) * 8;

    const f16* Ap = A + (size_t)(m0 + wr * 64 + r16) * K + kg;
    const f16* Bp = B + (size_t)(n0 + wc * 64 + r16) * K + kg;

    f32x4 acc[4][4];
#pragma unroll
    for (int i = 0; i < 4; i++)
#pragma unroll
        for (int j = 0; j < 4; j++) acc[i][j] = (f32x4){0.f, 0.f, 0.f, 0.f};

    for (int k0 = 0; k0 < K; k0 += 32) {
        f16x8 a[4], b[4];
#pragma unroll
        for (int i = 0; i < 4; i++)
            a[i] = *reinterpret_cast<const f16x8*>(Ap + (size_t)i * 16 * K + k0);
#pragma unroll
        for (int j = 0; j < 4; j++)
            b[j] = *reinterpret_cast<const f16x8*>(Bp + (size_t)j * 16 * K + k0);
#pragma unroll
        for (int i = 0; i < 4; i++)
#pragma unroll
            for (int j = 0; j < 4; j++)
                acc[i][j] = __builtin_amdgcn_mfma_f32_16x16x32_f16(a[i], b[j], acc[i][j], 0, 0, 0);
    }

    const int crow = m0 + wr * 64 + (lane >> 4) * 4;
    const int ccol = n0 + wc * 64 + r16;
#pragma unroll
    for (int i = 0; i < 4; i++) {
#pragma unroll
        for (int j = 0; j < 4; j++) {
            const int col = ccol + j * 16;
            const float sc = (col < scale_cols) ? scale : 1.f;
#pragma unroll
            for (int r = 0; r < 4; r++) {
                C[(size_t)(crow + i * 16 + r) * ldc + col] = (OT)(acc[i][j][r] * sc);
            }
        }
    }
}

// ---------------- gates: exact f32; stores (i_capped, log_sigmoid(f_capped)) ----------------
__global__ __launch_bounds__(256) void gate_kernel(const float* __restrict__ x,
                                                   const float* __restrict__ Wig,
                                                   const float* __restrict__ big,
                                                   const float* __restrict__ Wfg,
                                                   const float* __restrict__ bfg,
                                                   float* __restrict__ gates) {
    __shared__ float xs[4][D_MODEL];
    const int tid  = threadIdx.x;
    const int row0 = blockIdx.x * 4;
#pragma unroll
    for (int r = 0; r < 4; ++r) {
        const float4 v0 = *reinterpret_cast<const float4*>(&x[(size_t)(row0 + r) * D_MODEL + tid * 8]);
        const float4 v1 = *reinterpret_cast<const float4*>(&x[(size_t)(row0 + r) * D_MODEL + tid * 8 + 4]);
        *reinterpret_cast<float4*>(&xs[r][tid * 8])     = v0;
        *reinterpret_cast<float4*>(&xs[r][tid * 8 + 4]) = v1;
    }
    __syncthreads();

    const int o = tid >> 4;  // 0..15; o<8 -> i-gate head o, else f-gate head o-8
    const int t = tid & 15;
    const int head = o & 7;
    const bool is_i = (o < 8);
    const float* W = (is_i ? Wig : Wfg) + (size_t)head * D_MODEL;

    float a0 = 0.f, a1 = 0.f, a2 = 0.f, a3 = 0.f;
    for (int j = t * 128; j < t * 128 + 128; j += 4) {
        const float4 wv = *reinterpret_cast<const float4*>(&W[j]);
        const float4 xa = *reinterpret_cast<const float4*>(&xs[0][j]);
        const float4 xb = *reinterpret_cast<const float4*>(&xs[1][j]);
        const float4 xc = *reinterpret_cast<const float4*>(&xs[2][j]);
        const float4 xd = *reinterpret_cast<const float4*>(&xs[3][j]);
        a0 += wv.x * xa.x + wv.y * xa.y + wv.z * xa.z + wv.w * xa.w;
        a1 += wv.x * xb.x + wv.y * xb.y + wv.z * xb.z + wv.w * xb.w;
        a2 += wv.x * xc.x + wv.y * xc.y + wv.z * xc.z + wv.w * xc.w;
        a3 += wv.x * xd.x + wv.y * xd.y + wv.z * xd.z + wv.w * xd.w;
    }
#pragma unroll
    for (int off = 1; off < 16; off <<= 1) {
        a0 += __shfl_xor(a0, off);
        a1 += __shfl_xor(a1, off);
        a2 += __shfl_xor(a2, off);
        a3 += __shfl_xor(a3, off);
    }
    if (t == 0) {
        const float bias = is_i ? big[head] : bfg[head];
        float accs[4] = {a0, a1, a2, a3};
#pragma unroll
        for (int r = 0; r < 4; ++r) {
            const float pre = accs[r] + bias;
            const float capped = 15.f * tanhf(pre * (1.f / 15.f));
            float val;
            if (is_i) val = capped;
            else      val = fminf(capped, 0.f) - log1pf(expf(-fabsf(capped)));
            gates[(size_t)(row0 + r) * 16 + head * 2 + (is_i ? 0 : 1)] = val;
        }
    }
}

// ---------------- gate scan: per (b,h) max-plus scan, chunk decomposition ----------------
// gs4[bh][t] = (u_t, A_t, alpha_t, exp(-m_t)); gchunk[bh][j] = (F_j = alpha_last, G_j = A_last)
__global__ __launch_bounds__(64) void gate_scan(const float* __restrict__ gates,
                                                float4* __restrict__ gs4,
                                                float2* __restrict__ gchunk,
                                                float* __restrict__ mf) {
    const int bh = blockIdx.x;
    const int b = bh >> 3, h = bh & 7;
    const int l = threadIdx.x;
    __shared__ float2 comp[NCHUNK];
    if (l < NCHUNK) {
        const float* gp = gates + ((size_t)b * S_LEN + l * CHUNK) * 16 + h * 2;
        float bsum = 0.f, r = -1e30f;
        for (int s = 0; s < CHUNK; s++) {
            float2 g = *reinterpret_cast<const float2*>(gp + (size_t)s * 16);
            bsum += g.y;                  // f_log
            r = fmaxf(r, g.x - bsum);     // u_s = i_s - b_s
        }
        comp[l] = make_float2(bsum, r);
    }
    __syncthreads();
    if (l < NCHUNK) {
        float m0 = 0.f;   // m at chunk start (initial state m = 0)
        for (int c = 0; c < l; c++) m0 = comp[c].x + fmaxf(m0, comp[c].y);
        const float* gp = gates + ((size_t)b * S_LEN + l * CHUNK) * 16 + h * 2;
        float4* out = gs4 + (size_t)bh * S_LEN + l * CHUNK;
        float bsum = 0.f, r = -1e30f;
        float mlast = 0.f, Alast = 0.f, alast = 0.f;
        for (int s = 0; s < CHUNK; s++) {
            float2 g = *reinterpret_cast<const float2*>(gp + (size_t)s * 16);
            bsum += g.y;
            const float uu = g.x - bsum;
            r = fmaxf(r, uu);
            const float mx = fmaxf(m0, r);
            const float mt = bsum + mx;
            const float At = -mx;
            const float al = expf(m0 + At);
            out[s] = make_float4(uu, At, al, expf(-mt));
            if (s == CHUNK - 1) { mlast = mt; Alast = At; alast = al; }
        }
        gchunk[bh * NCHUNK + l] = make_float2(alast, Alast);
        if (l == NCHUNK - 1) mf[bh] = mlast;
    }
}

// ---------------- phase A: per (bh, chunk) intra attention + chunk summary ----------------
// S^T = mfma(K, Q); P = exp(A_t + u_s) .* S (s<=t); h_intra = P @ V; U = (gamma K)^T @ V
__global__ __launch_bounds__(256) void phaseA(const f16* __restrict__ qkvo,
                                              const float4* __restrict__ gs4,
                                              float* __restrict__ qn_intra,
                                              f16* __restrict__ Ubuf,
                                              f16* __restrict__ hintraT) {
    __shared__ f16 Kn[64][136];     // K natural [s][dq]  (dq = 0..127, +8 pad)
    __shared__ f16 KgT[128][72];    // gamma-scaled K^T [dq][s]
    __shared__ f16 VT[256][72];     // V^T [v][s]
    __shared__ f16 Pl[64][72];      // P [t][s]
    __shared__ float u_s[64], A_t[64];
    __shared__ float qnp[4][64];

    const int bid = blockIdx.x;
    const int bh = bid >> 5, ck = bid & 31;
    const int b = bh >> 3, h = bh & 7;
    const int tid = threadIdx.x;
    const int w = tid >> 6, l = tid & 63;

    const size_t rowbase = (size_t)b * S_LEN + ck * CHUNK;

    if (tid < 64) {
        float4 g = gs4[(size_t)bh * S_LEN + ck * CHUNK + tid];
        u_s[tid] = g.x; A_t[tid] = g.y;
    }
    const int sK = tid & 63, quad = tid >> 6;
    // stage K natural (keep regs for KgT)
    f16x8 kreg[4];
    {
        const f16* kp = qkvo + (rowbase + sK) * NCOL + 1024 + h * 128 + quad * 32;
#pragma unroll
        for (int i = 0; i < 4; i++) kreg[i] = *reinterpret_cast<const f16x8*>(kp + i * 8);
#pragma unroll
        for (int i = 0; i < 4; i++) *reinterpret_cast<f16x8*>(&Kn[sK][quad * 32 + i * 8]) = kreg[i];
    }
    // stage V^T
    {
        const f16* vp = qkvo + (rowbase + sK) * NCOL + 2048 + h * 256 + quad * 64;
#pragma unroll
        for (int i = 0; i < 8; i++) {
            f16x8 v = *reinterpret_cast<const f16x8*>(vp + i * 8);
#pragma unroll
            for (int e = 0; e < 8; e++) VT[quad * 64 + i * 8 + e][sK] = v[e];
        }
    }
    __syncthreads();
    // stage gamma-scaled K^T (gamma_s = exp(u_s + G), G = A_t[63])
    {
        const float gam = __expf(u_s[sK] + A_t[63]);
#pragma unroll
        for (int i = 0; i < 4; i++)
#pragma unroll
            for (int e = 0; e < 8; e++)
                KgT[quad * 32 + i * 8 + e][sK] = (f16)(gam * (float)kreg[i][e]);
    }
    // S^T mfma: A = Kn rows (wave's s-tile), B = Q (global)
    f16x8 af[4];
#pragma unroll
    for (int kk = 0; kk < 4; kk++)
        af[kk] = *reinterpret_cast<const f16x8*>(&Kn[w * 16 + (l & 15)][kk * 32 + (l >> 4) * 8]);
    f32x4 st[4];
#pragma unroll
    for (int ct = 0; ct < 4; ct++) {
        st[ct] = (f32x4){0.f, 0.f, 0.f, 0.f};
#pragma unroll
        for (int kk = 0; kk < 4; kk++) {
            const f16* qp = qkvo + (rowbase + ct * 16 + (l & 15)) * NCOL + h * 128 + kk * 32 + (l >> 4) * 8;
            f16x8 bf = *reinterpret_cast<const f16x8*>(qp);
            st[ct] = __builtin_amdgcn_mfma_f32_16x16x32_f16(af[kk], bf, st[ct], 0, 0, 0);
        }
    }
    // P^T: weights + mask; qn partials; write P to LDS (transposed -> natural [t][s])
#pragma unroll
    for (int ct = 0; ct < 4; ct++) {
        const int tloc = ct * 16 + (l & 15);
        const float At = A_t[tloc];
        float part = 0.f;
        f16x4 pk;
#pragma unroll
        for (int i = 0; i < 4; i++) {
            const int sloc = w * 16 + (l >> 4) * 4 + i;
            const float val = (sloc <= tloc) ? st[ct][i] * __expf(At + u_s[sloc]) : 0.f;
            part += val;
            pk[i] = (f16)val;
        }
        part += __shfl_xor(part, 16);
        part += __shfl_xor(part, 32);
        if ((l >> 4) == 0) qnp[w][tloc] = part;
        *reinterpret_cast<f16x4*>(&Pl[tloc][w * 16 + (l >> 4) * 4]) = pk;
    }
    __syncthreads();
    if (tid < 64)
        qn_intra[(size_t)bh * S_LEN + ck * CHUNK + tid] =
            qnp[0][tid] + qnp[1][tid] + qnp[2][tid] + qnp[3][tid];
    // PV: h_intra(64x256), wave w -> t-tile w
    {
        f16x8 pa[2];
#pragma unroll
        for (int kk = 0; kk < 2; kk++)
            pa[kk] = *reinterpret_cast<const f16x8*>(&Pl[w * 16 + (l & 15)][kk * 32 + (l >> 4) * 8]);
#pragma unroll
        for (int vt = 0; vt < 16; vt++) {
            f32x4 acc = (f32x4){0.f, 0.f, 0.f, 0.f};
#pragma unroll
            for (int kk = 0; kk < 2; kk++) {
                f16x8 vb = *reinterpret_cast<const f16x8*>(&VT[vt * 16 + (l & 15)][kk * 32 + (l >> 4) * 8]);
                acc = __builtin_amdgcn_mfma_f32_16x16x32_f16(pa[kk], vb, acc, 0, 0, 0);
            }
            f16x4 hk;
#pragma unroll
            for (int i = 0; i < 4; i++) hk[i] = (f16)acc[i];
            const size_t addr = ((size_t)bh * 256 + vt * 16 + (l & 15)) * S_LEN
                              + ck * CHUNK + w * 16 + (l >> 4) * 4;
            *reinterpret_cast<f16x4*>(&hintraT[addr]) = hk;
        }
    }
    // U (chunk summary, 128x256), stored as [dv][dq]; wave w -> dv-tiles w*4..w*4+3
#pragma unroll
    for (int q = 0; q < 4; q++) {
        const int dvt = w * 4 + q;
        f16x8 vb[2];
#pragma unroll
        for (int kk = 0; kk < 2; kk++)
            vb[kk] = *reinterpret_cast<const f16x8*>(&VT[dvt * 16 + (l & 15)][kk * 32 + (l >> 4) * 8]);
#pragma unroll
        for (int dqt = 0; dqt < 8; dqt++) {
            f32x4 acc = (f32x4){0.f, 0.f, 0.f, 0.f};
#pragma unroll
            for (int kk = 0; kk < 2; kk++) {
                f16x8 ka = *reinterpret_cast<const f16x8*>(&KgT[dqt * 16 + (l & 15)][kk * 32 + (l >> 4) * 8]);
                acc = __builtin_amdgcn_mfma_f32_16x16x32_f16(ka, vb[kk], acc, 0, 0, 0);
            }
            f16x4 uk;
#pragma unroll
            for (int i = 0; i < 4; i++) uk[i] = (f16)acc[i];
            const size_t addr = (((size_t)bh * NCHUNK + ck) * 256 + dvt * 16 + (l & 15)) * 128
                              + dqt * 16 + (l >> 4) * 4;
            *reinterpret_cast<f16x4*>(&Ubuf[addr]) = uk;
        }
    }
}

// ---------------- phase A2: n recurrence + denominators (per bh) ----------------
__global__ __launch_bounds__(256) void phaseA2(const f16* __restrict__ qkvo,
                                               const float4* __restrict__ gs4,
                                               const float2* __restrict__ gchunk,
                                               const float* __restrict__ qn_intra,
                                               float* __restrict__ rdenomb,
                                               float* __restrict__ nout) {
    const int bh = blockIdx.x;
    const int b = bh >> 3, h = bh & 7;
    const int tid = threadIdx.x;
    __shared__ float nsh[128];
    __shared__ float gam[64];
    __shared__ float upar[2][128];
    if (tid < 128) nsh[tid] = 0.f;
    __syncthreads();
    for (int ck = 0; ck < NCHUNK; ck++) {
        const float2 FG = gchunk[bh * NCHUNK + ck];
        if (tid < 64) gam[tid] = __expf(gs4[(size_t)bh * S_LEN + ck * CHUNK + tid].x + FG.y);
        // qn_inter with chunk-start n
        const int t = tid >> 2, dg = tid & 3;
        const int tg = ck * CHUNK + t;
        const f16* qp = qkvo + ((size_t)b * S_LEN + tg) * NCOL + h * 128 + dg * 32;
        float acc = 0.f;
#pragma unroll
        for (int dd = 0; dd < 4; dd++) {
            f16x8 qv = *reinterpret_cast<const f16x8*>(qp + dd * 8);
            const float* np = &nsh[dg * 32 + dd * 8];
#pragma unroll
            for (int e = 0; e < 8; e++) acc += (float)qv[e] * np[e];
        }
        acc += __shfl_xor(acc, 1);
        acc += __shfl_xor(acc, 2);
        if (dg == 0) {
            float4 g = gs4[(size_t)bh * S_LEN + tg];
            float qn = qn_intra[(size_t)bh * S_LEN + tg] + g.z * acc;
            rdenomb[(size_t)bh * S_LEN + tg] = 1.f / (fmaxf(fabsf(qn), g.w) + 1e-6f);
        }
        __syncthreads();
        // Un = sum_s gamma_s k_s
        const int d = tid & 127, sh = tid >> 7;
        const f16* kp = qkvo + ((size_t)b * S_LEN + ck * CHUNK + sh * 32) * NCOL + 1024 + h * 128 + d;
        float part = 0.f;
        for (int s = 0; s < 32; s++) part += gam[sh * 32 + s] * (float)kp[(size_t)s * NCOL];
        upar[sh][d] = part;
        __syncthreads();
        if (tid < 128) nsh[tid] = fmaf(FG.x, nsh[tid], upar[0][tid] + upar[1][tid]);
        __syncthreads();
    }
    if (tid < 128) nout[(size_t)bh * 128 + tid] = nsh[tid];
}

// ---------------- phase B: sequential inter-chunk C recurrence + output ----------------
__global__ __launch_bounds__(256) void phaseB(const f16* __restrict__ qkvo,
                                              const f16* __restrict__ Ubuf,
                                              const f16* __restrict__ hintraT,
                                              const float4* __restrict__ gs4,
                                              const float2* __restrict__ gchunk,
                                              const float* __restrict__ rdenomb,
                                              f16* __restrict__ hbuf,
                                              float* __restrict__ Cf) {
    const int bid = blockIdx.x;
    const int bh = bid >> 4, vt = bid & 15;
    const int b = bh >> 3, h = bh & 7;
    const int tid = threadIdx.x, w = tid >> 6, l = tid & 63;
    const int dv = vt * 16 + (l & 15);

    float c[4][8];
#pragma unroll
    for (int kk = 0; kk < 4; kk++)
#pragma unroll
        for (int j = 0; j < 8; j++) c[kk][j] = 0.f;

    for (int ck = 0; ck < NCHUNK; ck++) {
        // U fragments (match C's B-frag layout)
        f16x8 uf[4];
        const f16* ub = Ubuf + (((size_t)bh * NCHUNK + ck) * 256 + dv) * 128 + (l >> 4) * 8;
#pragma unroll
        for (int kk = 0; kk < 4; kk++) uf[kk] = *reinterpret_cast<const f16x8*>(ub + kk * 32);
        // Q fragments
        const int t0 = ck * CHUNK + w * 16;
        f16x8 af[4];
        const f16* qp = qkvo + ((size_t)b * S_LEN + t0 + (l & 15)) * NCOL + h * 128 + (l >> 4) * 8;
#pragma unroll
        for (int kk = 0; kk < 4; kk++) af[kk] = *reinterpret_cast<const f16x8*>(qp + kk * 32);
        // C -> f16 B-frags, H = Q @ C_in
        f16x8 cf[4];
#pragma unroll
        for (int kk = 0; kk < 4; kk++)
#pragma unroll
            for (int j = 0; j < 8; j++) cf[kk][j] = (f16)c[kk][j];
        f32x4 H = (f32x4){0.f, 0.f, 0.f, 0.f};
#pragma unroll
        for (int kk = 0; kk < 4; kk++)
            H = __builtin_amdgcn_mfma_f32_16x16x32_f16(af[kk], cf[kk], H, 0, 0, 0);
        // epilogue: h = (h_intra + alpha * h_inter) * rdenom
        const int tt = t0 + (l >> 4) * 4;
        f16x4 hi = *reinterpret_cast<const f16x4*>(&hintraT[((size_t)bh * 256 + dv) * S_LEN + tt]);
        float4 rd = *reinterpret_cast<const float4*>(&rdenomb[(size_t)bh * S_LEN + tt]);
        float al[4];
#pragma unroll
        for (int i = 0; i < 4; i++) al[i] = gs4[(size_t)bh * S_LEN + tt + i].z;
        const float rdv[4] = {rd.x, rd.y, rd.z, rd.w};
#pragma unroll
        for (int i = 0; i < 4; i++) {
            const float hval = ((float)hi[i] + al[i] * H[i]) * rdv[i];
            hbuf[((size_t)b * S_LEN + tt + i) * D_MODEL + h * 256 + dv] = (f16)hval;
        }
        // C = F*C + U
        const float F = gchunk[bh * NCHUNK + ck].x;
#pragma unroll
        for (int kk = 0; kk < 4; kk++)
#pragma unroll
            for (int j = 0; j < 8; j++) c[kk][j] = fmaf(F, c[kk][j], (float)uf[kk][j]);
    }
    if (w == 0) {
#pragma unroll
        for (int kk = 0; kk < 4; kk++)
#pragma unroll
            for (int j = 0; j < 8; j++) {
                const int dq = kk * 32 + (l >> 4) * 8 + j;
                Cf[((size_t)bh * 128 + dq) * 256 + dv] = c[kk][j];
            }
    }
}

// ---------------- per-head layernorm * gamma * sigmoid(og), f16 in/out ----------------
__global__ __launch_bounds__(256) void norm_kernel(const f16* __restrict__ hbuf,
                                                   const f16* __restrict__ qkvo,
                                                   const float* __restrict__ gamma,
                                                   f16* __restrict__ hout) {
    const int row = blockIdx.x;
    const int tid = threadIdx.x;
    const int g = tid >> 5;
    const int l = tid & 31;
    const f16* hrow = hbuf + (size_t)row * D_MODEL + g * 256 + l * 8;
    f16x8 hv8 = *reinterpret_cast<const f16x8*>(hrow);
    float hv[8];
#pragma unroll
    for (int e = 0; e < 8; e++) hv[e] = (float)hv8[e];
    float s = 0.f, s2 = 0.f;
#pragma unroll
    for (int e = 0; e < 8; e++) { s += hv[e]; s2 += hv[e] * hv[e]; }
#pragma unroll
    for (int off = 1; off < 32; off <<= 1) {
        s  += __shfl_xor(s, off);
        s2 += __shfl_xor(s2, off);
    }
    const float mu  = s * (1.f / 256.f);
    const float var = s2 * (1.f / 256.f) - mu * mu;
    const float rs  = rsqrtf(var + 1e-6f);
    const f16* ogr = qkvo + (size_t)row * NCOL + 4096 + g * 256 + l * 8;
    f16x8 og8 = *reinterpret_cast<const f16x8*>(ogr);
    const float* gam = gamma + g * 256 + l * 8;
    f16x8 o;
#pragma unroll
    for (int e = 0; e < 8; e++) {
        const float og  = (float)og8[e];
        const float sig = __builtin_amdgcn_rcpf(1.f + __expf(-og));
        const float hn  = (hv[e] - mu) * rs * gam[e];
        o[e] = (f16)(sig * hn);
    }
    *reinterpret_cast<f16x8*>(&hout[(size_t)row * D_MODEL + g * 256 + l * 8]) = o;
}

// ---------------- launch ----------------
extern "C" void kernel_launch(void* const* d_in, const int* in_sizes, int n_in,
                              void* d_out, int out_size, void* d_ws, size_t ws_size,
                              hipStream_t stream) {
    (void)in_sizes; (void)n_in; (void)out_size; (void)ws_size;
    const float* x     = (const float*)d_in[0];
    const float* Wq    = (const float*)d_in[1];
    const float* Wk    = (const float*)d_in[2];
    const float* Wv    = (const float*)d_in[3];
    const float* Wog   = (const float*)d_in[4];
    const float* Wig   = (const float*)d_in[5];
    const float* big   = (const float*)d_in[6];
    const float* Wfg   = (const float*)d_in[7];
    const float* bfg   = (const float*)d_in[8];
    const float* gamma = (const float*)d_in[9];
    const float* Wout  = (const float*)d_in[10];

    char* ws = (char*)d_ws;
    size_t off = 0;
    f16*    xf     = (f16*)(ws + off);    off += (size_t)NROWS * D_MODEL * 2;
    f16*    wcat   = (f16*)(ws + off);    off += (size_t)NCOL * D_MODEL * 2;
    f16*    woutf  = (f16*)(ws + off);    off += (size_t)D_MODEL * D_MODEL * 2;
    f16*    qkvo   = (f16*)(ws + off);    off += (size_t)NROWS * NCOL * 2;
    float*  gates  = (float*)(ws + off);  off += (size_t)NROWS * 16 * 4;
    float4* gs4    = (float4*)(ws + off); off += (size_t)16 * S_LEN * 16;
    float2* gchunk = (float2*)(ws + off); off += (size_t)16 * NCHUNK * 8;
    float*  qn_i   = (float*)(ws + off);  off += (size_t)16 * S_LEN * 4;
    float*  rden   = (float*)(ws + off);  off += (size_t)16 * S_LEN * 4;
    f16*    Ubuf   = (f16*)(ws + off);    off += (size_t)16 * NCHUNK * 256 * 128 * 2;
    f16*    hinT   = (f16*)(ws + off);    off += (size_t)16 * 256 * S_LEN * 2;
    f16*    hbuf   = (f16*)(ws + off);    off += (size_t)NROWS * D_MODEL * 2;
    f16*    houtf  = xf;  // xf dead after GEMM1

    float* y  = (float*)d_out;
    float* Cf = y + (size_t)NROWS * D_MODEL;
    float* nf = Cf + (size_t)16 * 128 * 256;
    float* mf = nf + (size_t)16 * 128;

    // casts
    cast_kernel<<<(NROWS * D_MODEL / 4 + 255) / 256, 256, 0, stream>>>(x, xf, NROWS * D_MODEL / 4);
    cast_kernel<<<(1024 * 2048 / 4 + 255) / 256, 256, 0, stream>>>(Wq, wcat, 1024 * 2048 / 4);
    cast_kernel<<<(1024 * 2048 / 4 + 255) / 256, 256, 0, stream>>>(Wk, wcat + (size_t)1024 * 2048, 1024 * 2048 / 4);
    cast_kernel<<<(2048 * 2048 / 4 + 255) / 256, 256, 0, stream>>>(Wv, wcat + (size_t)2048 * 2048, 2048 * 2048 / 4);
    cast_kernel<<<(2048 * 2048 / 4 + 255) / 256, 256, 0, stream>>>(Wog, wcat + (size_t)4096 * 2048, 2048 * 2048 / 4);
    cast_kernel<<<(2048 * 2048 / 4 + 255) / 256, 256, 0, stream>>>(Wout, woutf, 2048 * 2048 / 4);

    // gates (exact f32) + chunk decomposition
    gate_kernel<<<NROWS / 4, 256, 0, stream>>>(x, Wig, big, Wfg, bfg, gates);
    gate_scan<<<16, 64, 0, stream>>>(gates, gs4, gchunk, mf);

    // fused qkvo projection (f16 out); q columns pre-scaled by DQ^-0.5
    gemm_f16<f16><<<dim3(NCOL / 128, NROWS / 128), 256, 0, stream>>>(
        xf, wcat, qkvo, NROWS, NCOL, D_MODEL, NCOL, 1024, 0.08838834764831845f);

    // chunkwise mLSTM
    phaseA<<<512, 256, 0, stream>>>(qkvo, gs4, qn_i, Ubuf, hinT);
    phaseA2<<<16, 256, 0, stream>>>(qkvo, gs4, gchunk, qn_i, rden, nf);
    phaseB<<<256, 256, 0, stream>>>(qkvo, Ubuf, hinT, gs4, gchunk, rden, hbuf, Cf);

    // multihead norm + output gate
    norm_kernel<<<NROWS, 256, 0, stream>>>(hbuf, qkvo, gamma, houtf);

    // y = h_out @ Wout^T
    gemm_f16<float><<<dim3(D_MODEL / 128, NROWS / 128), 256, 0, stream>>>(
        houtf, woutf, y, NROWS, D_MODEL, D_MODEL, D_MODEL, 0, 1.f);
}

// Round 4
// 433.563 us; speedup vs baseline: 3.4519x; 1.6440x over previous
//
#include <hip/hip_runtime.h>

typedef _Float16 f16;
typedef f16 f16x8 __attribute__((ext_vector_type(8)));
typedef f16 f16x4 __attribute__((ext_vector_type(4)));
typedef float f32x4 __attribute__((ext_vector_type(4)));

#define S_LEN 2048
#define D_MODEL 2048
#define NHEADS 8
#define DQ 128
#define DV 256
#define NCOL 6144   // q(1024) | k(1024) | v(2048) | og(2048)
#define NROWS 4096  // B*S
#define CHUNK 64
#define NCHUNK 32   // per sequence

// ---------------- fused f32 -> f16 casts (x + all weights, one launch) ----------------
// float4-unit ranges: x:2097152 | Wq:524288 | Wk:524288 | Wv:1048576 | Wog:1048576 | Wout:1048576
__global__ __launch_bounds__(256) void cast_all(const float* __restrict__ x,
                                                const float* __restrict__ Wq,
                                                const float* __restrict__ Wk,
                                                const float* __restrict__ Wv,
                                                const float* __restrict__ Wog,
                                                const float* __restrict__ Wout,
                                                f16* __restrict__ xf,
                                                f16* __restrict__ wcat,
                                                f16* __restrict__ woutf) {
    int i = blockIdx.x * 256 + threadIdx.x;   // float4 index
    const float* src;
    f16* dst;
    int local;
    if (i < 2097152)      { src = x;    dst = xf;                        local = i; }
    else if (i < 2621440) { src = Wq;   dst = wcat;                      local = i - 2097152; }
    else if (i < 3145728) { src = Wk;   dst = wcat + (size_t)2097152;    local = i - 2621440; }
    else if (i < 4194304) { src = Wv;   dst = wcat + (size_t)4194304;    local = i - 3145728; }
    else if (i < 5242880) { src = Wog;  dst = wcat + (size_t)8388608;    local = i - 4194304; }
    else                  { src = Wout; dst = woutf;                     local = i - 5242880; }
    float4 v = reinterpret_cast<const float4*>(src)[local];
    f16x4 o = { (f16)v.x, (f16)v.y, (f16)v.z, (f16)v.w };
    reinterpret_cast<f16x4*>(dst)[local] = o;
}

// ---------------- GEMM: C[M,N] = A[M,K] @ B[N,K]^T  (f16 in, OT out) ----------------
// m97 structure: 128x128 tile, BK=32, 4 waves (2x2), LDS staging via global_load_lds,
// 2 barriers per K-step, 16 mfma_f32_16x16x32_f16 per K-step.
#define BK 32
template <typename OT>
__global__ __launch_bounds__(256) void gemm_f16(const f16* __restrict__ A,
                                                const f16* __restrict__ B,
                                                OT* __restrict__ C,
                                                int M, int N, int K, int ldc,
                                                int scale_cols, float scale) {
    __shared__ f16 As[128 * BK];   // 8 KB
    __shared__ f16 Bs[128 * BK];   // 8 KB
    const int tid  = threadIdx.x;
    const int lane = tid & 63;
    const int w    = tid >> 6;
    const int wr   = w >> 1, wc = w & 1;
    const int m0   = blockIdx.y * 128, n0 = blockIdx.x * 128;
    const int r16  = lane & 15;
    const int kg   = (lane >> 4) * 8;

    // staging map: issue covers 64 rows; thread t -> row = issue*64 + t/4, col = (t&3)*8
    const int srow = tid >> 2;
    const int scol = (tid & 3) * 8;
    const f16* Ag = A + (size_t)(m0 + srow) * K + scol;
    const f16* Bg = B + (size_t)(n0 + srow) * K + scol;
    // LDS dest (wave-uniform base + lane*16B): element base = issue*2048 + w*512
    f16* As0 = &As[w * 512];
    f16* Bs0 = &Bs[w * 512];

    f32x4 acc[4][4];
#pragma unroll
    for (int i = 0; i < 4; i++)
#pragma unroll
        for (int j = 0; j < 4; j++) acc[i][j] = (f32x4){0.f, 0.f, 0.f, 0.f};

    for (int k0 = 0; k0 < K; k0 += BK) {
        __syncthreads();   // previous iteration's compute done before overwrite
        __builtin_amdgcn_global_load_lds(
            (const __attribute__((address_space(1))) void*)(Ag + k0),
            (__attribute__((address_space(3))) void*)(As0), 16, 0, 0);
        __builtin_amdgcn_global_load_lds(
            (const __attribute__((address_space(1))) void*)(Ag + (size_t)64 * K + k0),
            (__attribute__((address_space(3))) void*)(As0 + 2048), 16, 0, 0);
        __builtin_amdgcn_global_load_lds(
            (const __attribute__((address_space(1))) void*)(Bg + k0),
            (__attribute__((address_space(3))) void*)(Bs0), 16, 0, 0);
        __builtin_amdgcn_global_load_lds(
            (const __attribute__((address_space(1))) void*)(Bg + (size_t)64 * K + k0),
            (__attribute__((address_space(3))) void*)(Bs0 + 2048), 16, 0, 0);
        __syncthreads();   // vmcnt(0) drain + barrier -> tile visible

        f16x8 a[4], b[4];
#pragma unroll
        for (int i = 0; i < 4; i++)
            a[i] = *reinterpret_cast<const f16x8*>(&As[(wr * 64 + i * 16 + r16) * BK + kg]);
#pragma unroll
        for (int j = 0; j < 4; j++)
            b[j] = *reinterpret_cast<const f16x8*>(&Bs[(wc * 64 + j * 16 + r16) * BK + kg]);
#pragma unroll
        for (int i = 0; i < 4; i++)
#pragma unroll
            for (int j = 0; j < 4; j++)
                acc[i][j] = __builtin_amdgcn_mfma_f32_16x16x32_f16(a[i], b[j], acc[i][j], 0, 0, 0);
    }

    const int crow = m0 + wr * 64 + (lane >> 4) * 4;
    const int ccol = n0 + wc * 64 + r16;
#pragma unroll
    for (int i = 0; i < 4; i++) {
#pragma unroll
        for (int j = 0; j < 4; j++) {
            const int col = ccol + j * 16;
            const float sc = (col < scale_cols) ? scale : 1.f;
#pragma unroll
            for (int r = 0; r < 4; r++) {
                C[(size_t)(crow + i * 16 + r) * ldc + col] = (OT)(acc[i][j][r] * sc);
            }
        }
    }
}

// ---------------- gates: exact f32; stores (i_capped, log_sigmoid(f_capped)) ----------------
__global__ __launch_bounds__(256) void gate_kernel(const float* __restrict__ x,
                                                   const float* __restrict__ Wig,
                                                   const float* __restrict__ big,
                                                   const float* __restrict__ Wfg,
                                                   const float* __restrict__ bfg,
                                                   float* __restrict__ gates) {
    __shared__ float xs[4][D_MODEL];
    const int tid  = threadIdx.x;
    const int row0 = blockIdx.x * 4;
#pragma unroll
    for (int r = 0; r < 4; ++r) {
        const float4 v0 = *reinterpret_cast<const float4*>(&x[(size_t)(row0 + r) * D_MODEL + tid * 8]);
        const float4 v1 = *reinterpret_cast<const float4*>(&x[(size_t)(row0 + r) * D_MODEL + tid * 8 + 4]);
        *reinterpret_cast<float4*>(&xs[r][tid * 8])     = v0;
        *reinterpret_cast<float4*>(&xs[r][tid * 8 + 4]) = v1;
    }
    __syncthreads();

    const int o = tid >> 4;  // 0..15; o<8 -> i-gate head o, else f-gate head o-8
    const int t = tid & 15;
    const int head = o & 7;
    const bool is_i = (o < 8);
    const float* W = (is_i ? Wig : Wfg) + (size_t)head * D_MODEL;

    float a0 = 0.f, a1 = 0.f, a2 = 0.f, a3 = 0.f;
    for (int j = t * 128; j < t * 128 + 128; j += 4) {
        const float4 wv = *reinterpret_cast<const float4*>(&W[j]);
        const float4 xa = *reinterpret_cast<const float4*>(&xs[0][j]);
        const float4 xb = *reinterpret_cast<const float4*>(&xs[1][j]);
        const float4 xc = *reinterpret_cast<const float4*>(&xs[2][j]);
        const float4 xd = *reinterpret_cast<const float4*>(&xs[3][j]);
        a0 += wv.x * xa.x + wv.y * xa.y + wv.z * xa.z + wv.w * xa.w;
        a1 += wv.x * xb.x + wv.y * xb.y + wv.z * xb.z + wv.w * xb.w;
        a2 += wv.x * xc.x + wv.y * xc.y + wv.z * xc.z + wv.w * xc.w;
        a3 += wv.x * xd.x + wv.y * xd.y + wv.z * xd.z + wv.w * xd.w;
    }
#pragma unroll
    for (int off = 1; off < 16; off <<= 1) {
        a0 += __shfl_xor(a0, off);
        a1 += __shfl_xor(a1, off);
        a2 += __shfl_xor(a2, off);
        a3 += __shfl_xor(a3, off);
    }
    if (t == 0) {
        const float bias = is_i ? big[head] : bfg[head];
        float accs[4] = {a0, a1, a2, a3};
#pragma unroll
        for (int r = 0; r < 4; ++r) {
            const float pre = accs[r] + bias;
            const float capped = 15.f * tanhf(pre * (1.f / 15.f));
            float val;
            if (is_i) val = capped;
            else      val = fminf(capped, 0.f) - log1pf(expf(-fabsf(capped)));
            gates[(size_t)(row0 + r) * 16 + head * 2 + (is_i ? 0 : 1)] = val;
        }
    }
}

// ---------------- gate scan: per (b,h) max-plus scan, chunk decomposition ----------------
// gs4[bh][t] = (u_t, A_t, alpha_t, exp(-m_t)); gchunk[bh][j] = (F_j = alpha_last, G_j = A_last)
__global__ __launch_bounds__(64) void gate_scan(const float* __restrict__ gates,
                                                float4* __restrict__ gs4,
                                                float2* __restrict__ gchunk,
                                                float* __restrict__ mf) {
    const int bh = blockIdx.x;
    const int b = bh >> 3, h = bh & 7;
    const int l = threadIdx.x;
    __shared__ float2 comp[NCHUNK];
    if (l < NCHUNK) {
        const float* gp = gates + ((size_t)b * S_LEN + l * CHUNK) * 16 + h * 2;
        float bsum = 0.f, r = -1e30f;
        for (int s = 0; s < CHUNK; s++) {
            float2 g = *reinterpret_cast<const float2*>(gp + (size_t)s * 16);
            bsum += g.y;                  // f_log
            r = fmaxf(r, g.x - bsum);     // u_s = i_s - b_s
        }
        comp[l] = make_float2(bsum, r);
    }
    __syncthreads();
    if (l < NCHUNK) {
        float m0 = 0.f;   // m at chunk start (initial state m = 0)
        for (int c = 0; c < l; c++) m0 = comp[c].x + fmaxf(m0, comp[c].y);
        const float* gp = gates + ((size_t)b * S_LEN + l * CHUNK) * 16 + h * 2;
        float4* out = gs4 + (size_t)bh * S_LEN + l * CHUNK;
        float bsum = 0.f, r = -1e30f;
        float mlast = 0.f, Alast = 0.f, alast = 0.f;
        for (int s = 0; s < CHUNK; s++) {
            float2 g = *reinterpret_cast<const float2*>(gp + (size_t)s * 16);
            bsum += g.y;
            const float uu = g.x - bsum;
            r = fmaxf(r, uu);
            const float mx = fmaxf(m0, r);
            const float mt = bsum + mx;
            const float At = -mx;
            const float al = expf(m0 + At);
            out[s] = make_float4(uu, At, al, expf(-mt));
            if (s == CHUNK - 1) { mlast = mt; Alast = At; alast = al; }
        }
        gchunk[bh * NCHUNK + l] = make_float2(alast, Alast);
        if (l == NCHUNK - 1) mf[bh] = mlast;
    }
}

// ---------------- phase A: per (bh, chunk) intra attention + chunk summary ----------------
// S^T = mfma(K, Q); P = exp(A_t + u_s) .* S (s<=t); h_intra = P @ V; U = (gamma K)^T @ V
__global__ __launch_bounds__(256) void phaseA(const f16* __restrict__ qkvo,
                                              const float4* __restrict__ gs4,
                                              float* __restrict__ qn_intra,
                                              f16* __restrict__ Ubuf,
                                              f16* __restrict__ hintraT) {
    __shared__ f16 Kn[64][136];     // K natural [s][dq]  (dq = 0..127, +8 pad)
    __shared__ f16 KgT[128][72];    // gamma-scaled K^T [dq][s]
    __shared__ f16 VT[256][72];     // V^T [v][s]
    __shared__ f16 Pl[64][72];      // P [t][s]
    __shared__ float u_s[64], A_t[64];
    __shared__ float qnp[4][64];

    const int bid = blockIdx.x;
    const int bh = bid >> 5, ck = bid & 31;
    const int b = bh >> 3, h = bh & 7;
    const int tid = threadIdx.x;
    const int w = tid >> 6, l = tid & 63;

    const size_t rowbase = (size_t)b * S_LEN + ck * CHUNK;

    if (tid < 64) {
        float4 g = gs4[(size_t)bh * S_LEN + ck * CHUNK + tid];
        u_s[tid] = g.x; A_t[tid] = g.y;
    }
    const int sK = tid & 63, quad = tid >> 6;
    // stage K natural (keep regs for KgT)
    f16x8 kreg[4];
    {
        const f16* kp = qkvo + (rowbase + sK) * NCOL + 1024 + h * 128 + quad * 32;
#pragma unroll
        for (int i = 0; i < 4; i++) kreg[i] = *reinterpret_cast<const f16x8*>(kp + i * 8);
#pragma unroll
        for (int i = 0; i < 4; i++) *reinterpret_cast<f16x8*>(&Kn[sK][quad * 32 + i * 8]) = kreg[i];
    }
    // stage V^T
    {
        const f16* vp = qkvo + (rowbase + sK) * NCOL + 2048 + h * 256 + quad * 64;
#pragma unroll
        for (int i = 0; i < 8; i++) {
            f16x8 v = *reinterpret_cast<const f16x8*>(vp + i * 8);
#pragma unroll
            for (int e = 0; e < 8; e++) VT[quad * 64 + i * 8 + e][sK] = v[e];
        }
    }
    __syncthreads();
    // stage gamma-scaled K^T (gamma_s = exp(u_s + G), G = A_t[63])
    {
        const float gam = __expf(u_s[sK] + A_t[63]);
#pragma unroll
        for (int i = 0; i < 4; i++)
#pragma unroll
            for (int e = 0; e < 8; e++)
                KgT[quad * 32 + i * 8 + e][sK] = (f16)(gam * (float)kreg[i][e]);
    }
    // S^T mfma: A = Kn rows (wave's s-tile), B = Q (global)
    f16x8 af[4];
#pragma unroll
    for (int kk = 0; kk < 4; kk++)
        af[kk] = *reinterpret_cast<const f16x8*>(&Kn[w * 16 + (l & 15)][kk * 32 + (l >> 4) * 8]);
    f32x4 st[4];
#pragma unroll
    for (int ct = 0; ct < 4; ct++) {
        st[ct] = (f32x4){0.f, 0.f, 0.f, 0.f};
#pragma unroll
        for (int kk = 0; kk < 4; kk++) {
            const f16* qp = qkvo + (rowbase + ct * 16 + (l & 15)) * NCOL + h * 128 + kk * 32 + (l >> 4) * 8;
            f16x8 bf = *reinterpret_cast<const f16x8*>(qp);
            st[ct] = __builtin_amdgcn_mfma_f32_16x16x32_f16(af[kk], bf, st[ct], 0, 0, 0);
        }
    }
    // P^T: weights + mask; qn partials; write P to LDS (transposed -> natural [t][s])
#pragma unroll
    for (int ct = 0; ct < 4; ct++) {
        const int tloc = ct * 16 + (l & 15);
        const float At = A_t[tloc];
        float part = 0.f;
        f16x4 pk;
#pragma unroll
        for (int i = 0; i < 4; i++) {
            const int sloc = w * 16 + (l >> 4) * 4 + i;
            const float val = (sloc <= tloc) ? st[ct][i] * __expf(At + u_s[sloc]) : 0.f;
            part += val;
            pk[i] = (f16)val;
        }
        part += __shfl_xor(part, 16);
        part += __shfl_xor(part, 32);
        if ((l >> 4) == 0) qnp[w][tloc] = part;
        *reinterpret_cast<f16x4*>(&Pl[tloc][w * 16 + (l >> 4) * 4]) = pk;
    }
    __syncthreads();
    if (tid < 64)
        qn_intra[(size_t)bh * S_LEN + ck * CHUNK + tid] =
            qnp[0][tid] + qnp[1][tid] + qnp[2][tid] + qnp[3][tid];
    // PV: h_intra(64x256), wave w -> t-tile w
    {
        f16x8 pa[2];
#pragma unroll
        for (int kk = 0; kk < 2; kk++)
            pa[kk] = *reinterpret_cast<const f16x8*>(&Pl[w * 16 + (l & 15)][kk * 32 + (l >> 4) * 8]);
#pragma unroll
        for (int vt = 0; vt < 16; vt++) {
            f32x4 acc = (f32x4){0.f, 0.f, 0.f, 0.f};
#pragma unroll
            for (int kk = 0; kk < 2; kk++) {
                f16x8 vb = *reinterpret_cast<const f16x8*>(&VT[vt * 16 + (l & 15)][kk * 32 + (l >> 4) * 8]);
                acc = __builtin_amdgcn_mfma_f32_16x16x32_f16(pa[kk], vb, acc, 0, 0, 0);
            }
            f16x4 hk;
#pragma unroll
            for (int i = 0; i < 4; i++) hk[i] = (f16)acc[i];
            const size_t addr = ((size_t)bh * 256 + vt * 16 + (l & 15)) * S_LEN
                              + ck * CHUNK + w * 16 + (l >> 4) * 4;
            *reinterpret_cast<f16x4*>(&hintraT[addr]) = hk;
        }
    }
    // U (chunk summary, 128x256), stored as [dv][dq]; wave w -> dv-tiles w*4..w*4+3
#pragma unroll
    for (int q = 0; q < 4; q++) {
        const int dvt = w * 4 + q;
        f16x8 vb[2];
#pragma unroll
        for (int kk = 0; kk < 2; kk++)
            vb[kk] = *reinterpret_cast<const f16x8*>(&VT[dvt * 16 + (l & 15)][kk * 32 + (l >> 4) * 8]);
#pragma unroll
        for (int dqt = 0; dqt < 8; dqt++) {
            f32x4 acc = (f32x4){0.f, 0.f, 0.f, 0.f};
#pragma unroll
            for (int kk = 0; kk < 2; kk++) {
                f16x8 ka = *reinterpret_cast<const f16x8*>(&KgT[dqt * 16 + (l & 15)][kk * 32 + (l >> 4) * 8]);
                acc = __builtin_amdgcn_mfma_f32_16x16x32_f16(ka, vb[kk], acc, 0, 0, 0);
            }
            f16x4 uk;
#pragma unroll
            for (int i = 0; i < 4; i++) uk[i] = (f16)acc[i];
            const size_t addr = (((size_t)bh * NCHUNK + ck) * 256 + dvt * 16 + (l & 15)) * 128
                              + dqt * 16 + (l >> 4) * 4;
            *reinterpret_cast<f16x4*>(&Ubuf[addr]) = uk;
        }
    }
}

// ---------------- phase A2: n recurrence + denominators (per bh) ----------------
__global__ __launch_bounds__(256) void phaseA2(const f16* __restrict__ qkvo,
                                               const float4* __restrict__ gs4,
                                               const float2* __restrict__ gchunk,
                                               const float* __restrict__ qn_intra,
                                               float* __restrict__ rdenomb,
                                               float* __restrict__ nout) {
    const int bh = blockIdx.x;
    const int b = bh >> 3, h = bh & 7;
    const int tid = threadIdx.x;
    __shared__ float nsh[128];
    __shared__ float gam[64];
    __shared__ float upar[2][128];
    if (tid < 128) nsh[tid] = 0.f;
    __syncthreads();
    for (int ck = 0; ck < NCHUNK; ck++) {
        const float2 FG = gchunk[bh * NCHUNK + ck];
        if (tid < 64) gam[tid] = __expf(gs4[(size_t)bh * S_LEN + ck * CHUNK + tid].x + FG.y);
        // qn_inter with chunk-start n
        const int t = tid >> 2, dg = tid & 3;
        const int tg = ck * CHUNK + t;
        const f16* qp = qkvo + ((size_t)b * S_LEN + tg) * NCOL + h * 128 + dg * 32;
        float acc = 0.f;
#pragma unroll
        for (int dd = 0; dd < 4; dd++) {
            f16x8 qv = *reinterpret_cast<const f16x8*>(qp + dd * 8);
            const float* np = &nsh[dg * 32 + dd * 8];
#pragma unroll
            for (int e = 0; e < 8; e++) acc += (float)qv[e] * np[e];
        }
        acc += __shfl_xor(acc, 1);
        acc += __shfl_xor(acc, 2);
        if (dg == 0) {
            float4 g = gs4[(size_t)bh * S_LEN + tg];
            float qn = qn_intra[(size_t)bh * S_LEN + tg] + g.z * acc;
            rdenomb[(size_t)bh * S_LEN + tg] = 1.f / (fmaxf(fabsf(qn), g.w) + 1e-6f);
        }
        __syncthreads();
        // Un = sum_s gamma_s k_s
        const int d = tid & 127, sh = tid >> 7;
        const f16* kp = qkvo + ((size_t)b * S_LEN + ck * CHUNK + sh * 32) * NCOL + 1024 + h * 128 + d;
        float part = 0.f;
        for (int s = 0; s < 32; s++) part += gam[sh * 32 + s] * (float)kp[(size_t)s * NCOL];
        upar[sh][d] = part;
        __syncthreads();
        if (tid < 128) nsh[tid] = fmaf(FG.x, nsh[tid], upar[0][tid] + upar[1][tid]);
        __syncthreads();
    }
    if (tid < 128) nout[(size_t)bh * 128 + tid] = nsh[tid];
}

// ---------------- phase B: sequential inter-chunk C recurrence + output ----------------
__global__ __launch_bounds__(256) void phaseB(const f16* __restrict__ qkvo,
                                              const f16* __restrict__ Ubuf,
                                              const f16* __restrict__ hintraT,
                                              const float4* __restrict__ gs4,
                                              const float2* __restrict__ gchunk,
                                              const float* __restrict__ rdenomb,
                                              f16* __restrict__ hbuf,
                                              float* __restrict__ Cf) {
    const int bid = blockIdx.x;
    const int bh = bid >> 4, vt = bid & 15;
    const int b = bh >> 3, h = bh & 7;
    const int tid = threadIdx.x, w = tid >> 6, l = tid & 63;
    const int dv = vt * 16 + (l & 15);

    float c[4][8];
#pragma unroll
    for (int kk = 0; kk < 4; kk++)
#pragma unroll
        for (int j = 0; j < 8; j++) c[kk][j] = 0.f;

    for (int ck = 0; ck < NCHUNK; ck++) {
        // U fragments (match C's B-frag layout)
        f16x8 uf[4];
        const f16* ub = Ubuf + (((size_t)bh * NCHUNK + ck) * 256 + dv) * 128 + (l >> 4) * 8;
#pragma unroll
        for (int kk = 0; kk < 4; kk++) uf[kk] = *reinterpret_cast<const f16x8*>(ub + kk * 32);
        // Q fragments
        const int t0 = ck * CHUNK + w * 16;
        f16x8 af[4];
        const f16* qp = qkvo + ((size_t)b * S_LEN + t0 + (l & 15)) * NCOL + h * 128 + (l >> 4) * 8;
#pragma unroll
        for (int kk = 0; kk < 4; kk++) af[kk] = *reinterpret_cast<const f16x8*>(qp + kk * 32);
        // C -> f16 B-frags, H = Q @ C_in
        f16x8 cf[4];
#pragma unroll
        for (int kk = 0; kk < 4; kk++)
#pragma unroll
            for (int j = 0; j < 8; j++) cf[kk][j] = (f16)c[kk][j];
        f32x4 H = (f32x4){0.f, 0.f, 0.f, 0.f};
#pragma unroll
        for (int kk = 0; kk < 4; kk++)
            H = __builtin_amdgcn_mfma_f32_16x16x32_f16(af[kk], cf[kk], H, 0, 0, 0);
        // epilogue: h = (h_intra + alpha * h_inter) * rdenom
        const int tt = t0 + (l >> 4) * 4;
        f16x4 hi = *reinterpret_cast<const f16x4*>(&hintraT[((size_t)bh * 256 + dv) * S_LEN + tt]);
        float4 rd = *reinterpret_cast<const float4*>(&rdenomb[(size_t)bh * S_LEN + tt]);
        float al[4];
#pragma unroll
        for (int i = 0; i < 4; i++) al[i] = gs4[(size_t)bh * S_LEN + tt + i].z;
        const float rdv[4] = {rd.x, rd.y, rd.z, rd.w};
#pragma unroll
        for (int i = 0; i < 4; i++) {
            const float hval = ((float)hi[i] + al[i] * H[i]) * rdv[i];
            hbuf[((size_t)b * S_LEN + tt + i) * D_MODEL + h * 256 + dv] = (f16)hval;
        }
        // C = F*C + U
        const float F = gchunk[bh * NCHUNK + ck].x;
#pragma unroll
        for (int kk = 0; kk < 4; kk++)
#pragma unroll
            for (int j = 0; j < 8; j++) c[kk][j] = fmaf(F, c[kk][j], (float)uf[kk][j]);
    }
    if (w == 0) {
#pragma unroll
        for (int kk = 0; kk < 4; kk++)
#pragma unroll
            for (int j = 0; j < 8; j++) {
                const int dq = kk * 32 + (l >> 4) * 8 + j;
                Cf[((size_t)bh * 128 + dq) * 256 + dv] = c[kk][j];
            }
    }
}

// ---------------- per-head layernorm * gamma * sigmoid(og), f16 in/out ----------------
__global__ __launch_bounds__(256) void norm_kernel(const f16* __restrict__ hbuf,
                                                   const f16* __restrict__ qkvo,
                                                   const float* __restrict__ gamma,
                                                   f16* __restrict__ hout) {
    const int row = blockIdx.x;
    const int tid = threadIdx.x;
    const int g = tid >> 5;
    const int l = tid & 31;
    const f16* hrow = hbuf + (size_t)row * D_MODEL + g * 256 + l * 8;
    f16x8 hv8 = *reinterpret_cast<const f16x8*>(hrow);
    float hv[8];
#pragma unroll
    for (int e = 0; e < 8; e++) hv[e] = (float)hv8[e];
    float s = 0.f, s2 = 0.f;
#pragma unroll
    for (int e = 0; e < 8; e++) { s += hv[e]; s2 += hv[e] * hv[e]; }
#pragma unroll
    for (int off = 1; off < 32; off <<= 1) {
        s  += __shfl_xor(s, off);
        s2 += __shfl_xor(s2, off);
    }
    const float mu  = s * (1.f / 256.f);
    const float var = s2 * (1.f / 256.f) - mu * mu;
    const float rs  = rsqrtf(var + 1e-6f);
    const f16* ogr = qkvo + (size_t)row * NCOL + 4096 + g * 256 + l * 8;
    f16x8 og8 = *reinterpret_cast<const f16x8*>(ogr);
    const float* gam = gamma + g * 256 + l * 8;
    f16x8 o;
#pragma unroll
    for (int e = 0; e < 8; e++) {
        const float og  = (float)og8[e];
        const float sig = __builtin_amdgcn_rcpf(1.f + __expf(-og));
        const float hn  = (hv[e] - mu) * rs * gam[e];
        o[e] = (f16)(sig * hn);
    }
    *reinterpret_cast<f16x8*>(&hout[(size_t)row * D_MODEL + g * 256 + l * 8]) = o;
}

// ---------------- launch ----------------
extern "C" void kernel_launch(void* const* d_in, const int* in_sizes, int n_in,
                              void* d_out, int out_size, void* d_ws, size_t ws_size,
                              hipStream_t stream) {
    (void)in_sizes; (void)n_in; (void)out_size; (void)ws_size;
    const float* x     = (const float*)d_in[0];
    const float* Wq    = (const float*)d_in[1];
    const float* Wk    = (const float*)d_in[2];
    const float* Wv    = (const float*)d_in[3];
    const float* Wog   = (const float*)d_in[4];
    const float* Wig   = (const float*)d_in[5];
    const float* big   = (const float*)d_in[6];
    const float* Wfg   = (const float*)d_in[7];
    const float* bfg   = (const float*)d_in[8];
    const float* gamma = (const float*)d_in[9];
    const float* Wout  = (const float*)d_in[10];

    char* ws = (char*)d_ws;
    size_t off = 0;
    f16*    xf     = (f16*)(ws + off);    off += (size_t)NROWS * D_MODEL * 2;
    f16*    wcat   = (f16*)(ws + off);    off += (size_t)NCOL * D_MODEL * 2;
    f16*    woutf  = (f16*)(ws + off);    off += (size_t)D_MODEL * D_MODEL * 2;
    f16*    qkvo   = (f16*)(ws + off);    off += (size_t)NROWS * NCOL * 2;
    float*  gates  = (float*)(ws + off);  off += (size_t)NROWS * 16 * 4;
    float4* gs4    = (float4*)(ws + off); off += (size_t)16 * S_LEN * 16;
    float2* gchunk = (float2*)(ws + off); off += (size_t)16 * NCHUNK * 8;
    float*  qn_i   = (float*)(ws + off);  off += (size_t)16 * S_LEN * 4;
    float*  rden   = (float*)(ws + off);  off += (size_t)16 * S_LEN * 4;
    f16*    Ubuf   = (f16*)(ws + off);    off += (size_t)16 * NCHUNK * 256 * 128 * 2;
    f16*    hinT   = (f16*)(ws + off);    off += (size_t)16 * 256 * S_LEN * 2;
    f16*    hbuf   = (f16*)(ws + off);    off += (size_t)NROWS * D_MODEL * 2;
    f16*    houtf  = xf;  // xf dead after GEMM1

    float* y  = (float*)d_out;
    float* Cf = y + (size_t)NROWS * D_MODEL;
    float* nf = Cf + (size_t)16 * 128 * 256;
    float* mf = nf + (size_t)16 * 128;

    // fused casts (x + all weights)
    cast_all<<<24576, 256, 0, stream>>>(x, Wq, Wk, Wv, Wog, Wout, xf, wcat, woutf);

    // gates (exact f32) + chunk decomposition
    gate_kernel<<<NROWS / 4, 256, 0, stream>>>(x, Wig, big, Wfg, bfg, gates);
    gate_scan<<<16, 64, 0, stream>>>(gates, gs4, gchunk, mf);

    // fused qkvo projection (f16 out); q columns pre-scaled by DQ^-0.5
    gemm_f16<f16><<<dim3(NCOL / 128, NROWS / 128), 256, 0, stream>>>(
        xf, wcat, qkvo, NROWS, NCOL, D_MODEL, NCOL, 1024, 0.08838834764831845f);

    // chunkwise mLSTM
    phaseA<<<512, 256, 0, stream>>>(qkvo, gs4, qn_i, Ubuf, hinT);
    phaseA2<<<16, 256, 0, stream>>>(qkvo, gs4, gchunk, qn_i, rden, nf);
    phaseB<<<256, 256, 0, stream>>>(qkvo, Ubuf, hinT, gs4, gchunk, rden, hbuf, Cf);

    // multihead norm + output gate
    norm_kernel<<<NROWS, 256, 0, stream>>>(hbuf, qkvo, gamma, houtf);

    // y = h_out @ Wout^T
    gemm_f16<float><<<dim3(D_MODEL / 128, NROWS / 128), 256, 0, stream>>>(
        houtf, woutf, y, NROWS, D_MODEL, D_MODEL, D_MODEL, 0, 1.f);
}